// Round 2
// baseline (165.039 us; speedup 1.0000x reference)
//
#include <hip/hip_runtime.h>

// Problem constants (fixed by the reference)
#define B_   64
#define S_   512
#define P_   300
#define K_   50
#define MPAD 64      // label dim padded to 64 for MFMA M
#define LDX  344     // x_tile row stride in bf16 elems (16B-aligned rows, bank-balanced)
#define LDG  528     // k3 LDS row stride in shorts: 8 halo + 512 + 8 halo (16B-mult)

typedef short short8v __attribute__((ext_vector_type(8)));
typedef float float4v __attribute__((ext_vector_type(4)));

__device__ __forceinline__ short f2bf(float f) {
  unsigned u = __builtin_bit_cast(unsigned, f);
  u = (u + 0x7FFFu + ((u >> 16) & 1u)) >> 16;  // RNE
  return (short)u;
}
__device__ __forceinline__ float bf2f(short h) {
  return __builtin_bit_cast(float, ((unsigned)(unsigned short)h) << 16);
}

// ---------------------------------------------------------------------------
// K1: normalize C -> l_hat, pad {l_hat, W2} to 64x320 bf16 (zeros), and pack
// into MFMA A-fragment order so K2's A loads are coalesced 16B/lane.
// apack layout: [(mat*4 + mtile)*10 + kstep][lane][8 bf16]
// grid 80 blocks (mat 2 x mtile 4 x kstep 10) x 64 threads.
// ---------------------------------------------------------------------------
__global__ __launch_bounds__(64) void k1_prep(const float* __restrict__ C,
                                              const float* __restrict__ W2,
                                              short* __restrict__ apack) {
  int bid = blockIdx.x;
  int mat = bid / 40;
  int rem = bid - mat * 40;
  int mt  = rem / 10;
  int ks  = rem - mt * 10;
  int lane = threadIdx.x;
  __shared__ float invn[16];
  if (mat == 0) {
    int rl = lane >> 2, q = lane & 3;
    int m = mt * 16 + rl;
    float ss = 0.f;
    if (m < K_) {
      for (int p = q; p < P_; p += 4) { float v = C[m * P_ + p]; ss += v * v; }
    }
    ss += __shfl_xor(ss, 1);
    ss += __shfl_xor(ss, 2);
    if (q == 0) invn[rl] = 1.f / (sqrtf(ss) + 0.001f);
  }
  __syncthreads();
  int ml = lane & 15, quad = lane >> 4;
  int m = mt * 16 + ml;
  const float* src = (mat == 0) ? C : W2;
  short8v v8;
  #pragma unroll
  for (int j = 0; j < 8; ++j) {
    int k = ks * 32 + quad * 8 + j;
    float v = 0.f;
    if (m < K_ && k < P_) {
      v = src[m * P_ + k];
      if (mat == 0) v *= invn[ml];
    }
    v8[j] = f2bf(v);
  }
  *(short8v*)(apack + (size_t)(((mat * 4 + mt) * 10 + ks) * 512 + lane * 8)) = v8;
}

// ---------------------------------------------------------------------------
// K2: per (b, 64-s chunk): gather emb rows -> LDS bf16 (f32 norms en route),
// dual GEMM via 16x16x32 bf16 MFMA:
//   G[b,m,s]  = bf16( (l_hat . x) * 1/(||x||+1e-3) )
//   Yt[b,m,s] = bf16( W2 . x )
// grid 512 x 256. Wave w owns M-rows [16w,16w+16). Only m<50 stored.
// ---------------------------------------------------------------------------
__global__ __launch_bounds__(256) void k2_gemm(const int* __restrict__ idx,
                                               const float* __restrict__ emb,
                                               const short* __restrict__ apack,
                                               short* __restrict__ G,
                                               short* __restrict__ Yt) {
  __shared__ __align__(16) short xt[64][LDX];
  __shared__ float scale_s[64];
  int bid = blockIdx.x;
  int b = bid >> 3, s0 = (bid & 7) * 64;
  int tid = threadIdx.x;
  int w = tid >> 6, lane = tid & 63;

  // stage: wave w loads rows [16w, 16w+16)
  float ssr[16];
  #pragma unroll
  for (int r = 0; r < 16; ++r) {
    int ls = w * 16 + r;
    int row = idx[b * S_ + s0 + ls];
    const float4* src = (const float4*)(emb + (size_t)row * P_);
    float4 v = src[lane];                       // p = 4*lane .. 4*lane+3 (p<256)
    float ss = v.x * v.x + v.y * v.y + v.z * v.z + v.w * v.w;
    short4 h; h.x = f2bf(v.x); h.y = f2bf(v.y); h.z = f2bf(v.z); h.w = f2bf(v.w);
    *(short4*)&xt[ls][4 * lane] = h;
    if (lane < 11) {                            // p = 256..299
      float4 v2 = src[64 + lane];
      ss += v2.x * v2.x + v2.y * v2.y + v2.z * v2.z + v2.w * v2.w;
      short4 h2; h2.x = f2bf(v2.x); h2.y = f2bf(v2.y); h2.z = f2bf(v2.z); h2.w = f2bf(v2.w);
      *(short4*)&xt[ls][256 + 4 * lane] = h2;
    } else if (lane < 16) {                     // zero K-pad cols 300..319
      short4 z = {0, 0, 0, 0};
      *(short4*)&xt[ls][300 + 4 * (lane - 11)] = z;
    }
    ssr[r] = ss;
  }
  #pragma unroll
  for (int r = 0; r < 16; ++r) {
    float ss = ssr[r];
    #pragma unroll
    for (int off = 32; off > 0; off >>= 1) ss += __shfl_xor(ss, off);
    if (lane == 0) scale_s[w * 16 + r] = 1.f / (sqrtf(ss) + 0.001f);
  }
  __syncthreads();

  float4v accG[4] = {}, accY[4] = {};
  int ml = lane & 15, quad = lane >> 4;
  const short8v* a1p = (const short8v*)(apack) + (size_t)((0 * 4 + w) * 10) * 64 + lane;
  const short8v* a2p = (const short8v*)(apack) + (size_t)((1 * 4 + w) * 10) * 64 + lane;
  #pragma unroll
  for (int ks = 0; ks < 10; ++ks) {
    short8v a1 = a1p[ks * 64];
    short8v a2 = a2p[ks * 64];
    int kk = ks * 32 + quad * 8;
    #pragma unroll
    for (int nt = 0; nt < 4; ++nt) {
      short8v bf = *(const short8v*)&xt[nt * 16 + ml][kk];
      accG[nt] = __builtin_amdgcn_mfma_f32_16x16x32_bf16(a1, bf, accG[nt], 0, 0, 0);
      accY[nt] = __builtin_amdgcn_mfma_f32_16x16x32_bf16(a2, bf, accY[nt], 0, 0, 0);
    }
  }

  // epilogue: C/D layout col = lane&15, row = quad*4+reg; store bf16, m<50 only
  #pragma unroll
  for (int nt = 0; nt < 4; ++nt) {
    int sl = nt * 16 + ml;
    float sc = scale_s[sl];
    int sg = s0 + sl;
    #pragma unroll
    for (int reg = 0; reg < 4; ++reg) {
      int m = w * 16 + quad * 4 + reg;
      if (m < K_) {
        G [(size_t)(b * MPAD + m) * S_ + sg] = f2bf(accG[nt][reg] * sc);
        Yt[(size_t)(b * MPAD + m) * S_ + sg] = f2bf(accY[nt][reg]);
      }
    }
  }
}

// ---------------------------------------------------------------------------
// K3 (fused): one block per b (512 threads).
//   stage G[b] (bf16, halo-padded) in LDS
//   m[s]  = max_{k<50} relu(conv11(G[b,k,s-5..s+5]) + conv_b)   (thread = s)
//   beta  = softmax(m)/S                                        (block reduce)
//   out[b,k] = sum_s beta[s]*Yt[b,k,s] + b2[k]                  (wave per k)
// ---------------------------------------------------------------------------
__global__ __launch_bounds__(512) void k3_fused(const short* __restrict__ G,
                                                const float* __restrict__ conv_w,
                                                const float* __restrict__ conv_b,
                                                const short* __restrict__ Yt,
                                                const float* __restrict__ b2,
                                                float* __restrict__ out) {
  __shared__ __align__(16) short gt[K_][LDG];
  __shared__ float beta[S_];
  __shared__ float red[8];
  int b = blockIdx.x;
  int tid = threadIdx.x;
  int lane = tid & 63, wv = tid >> 6;

  // zero halos: gt[k][0..8) and gt[k][520..528)
  for (int e = tid; e < K_ * 8; e += 512) {
    int k = e >> 3, j = e & 7;
    gt[k][j] = 0;
    gt[k][520 + j] = 0;
  }
  // stage rows: wave wv loads rows wv, wv+8, ... ; lane covers 8 shorts (16B)
  for (int k = wv; k < K_; k += 8) {
    short8v v = *(const short8v*)(G + (((size_t)(b * MPAD + k)) << 9) + lane * 8);
    *(short8v*)&gt[k][8 + lane * 8] = v;
  }
  float wvv[11];
  #pragma unroll
  for (int t = 0; t < 11; ++t) wvv[t] = conv_w[t];
  float cb = conv_b[0];
  __syncthreads();

  // conv + relu + max over k; thread owns s = tid
  float mx = 0.f;  // relu >= 0 so 0 is a safe identity
  for (int k = 0; k < K_; ++k) {
    float acc = cb;
    #pragma unroll
    for (int t = 0; t < 11; ++t) acc += wvv[t] * bf2f(gt[k][3 + tid + t]);
    mx = fmaxf(mx, fmaxf(acc, 0.f));
  }

  // block softmax over s (512 threads)
  float r = mx;
  #pragma unroll
  for (int off = 32; off > 0; off >>= 1) r = fmaxf(r, __shfl_xor(r, off));
  if (lane == 0) red[wv] = r;
  __syncthreads();
  float bm = red[0];
  #pragma unroll
  for (int i = 1; i < 8; ++i) bm = fmaxf(bm, red[i]);
  float e = __expf(mx - bm);
  r = e;
  #pragma unroll
  for (int off = 32; off > 0; off >>= 1) r += __shfl_xor(r, off);
  __syncthreads();               // everyone done reading red (max) before rewrite
  if (lane == 0) red[wv] = r;
  __syncthreads();
  float sum = 0.f;
  #pragma unroll
  for (int i = 0; i < 8; ++i) sum += red[i];
  beta[tid] = e / (sum * (float)S_);   // fold 1/S of jnp.mean into beta
  __syncthreads();

  // out[b,k] = sum_s beta[s] * Yt[b,k,s] + b2[k]; wave wv handles k = wv, wv+8, ...
  for (int k = wv; k < K_; k += 8) {
    short8v y = *(const short8v*)(Yt + (((size_t)(b * MPAD + k)) << 9) + lane * 8);
    const float4* bp = (const float4*)&beta[lane * 8];
    float4 b0 = bp[0], b1 = bp[1];
    float acc = b0.x * bf2f(y[0]) + b0.y * bf2f(y[1]) +
                b0.z * bf2f(y[2]) + b0.w * bf2f(y[3]) +
                b1.x * bf2f(y[4]) + b1.y * bf2f(y[5]) +
                b1.z * bf2f(y[6]) + b1.w * bf2f(y[7]);
    #pragma unroll
    for (int off = 32; off > 0; off >>= 1) acc += __shfl_xor(acc, off);
    if (lane == 0) out[b * K_ + k] = acc + b2[k];
  }
}

// ---------------------------------------------------------------------------
extern "C" void kernel_launch(void* const* d_in, const int* in_sizes, int n_in,
                              void* d_out, int out_size, void* d_ws, size_t ws_size,
                              hipStream_t stream) {
  const int*   idx    = (const int*)  d_in[0];
  const float* emb    = (const float*)d_in[1];
  const float* C      = (const float*)d_in[2];
  const float* conv_w = (const float*)d_in[3];
  const float* conv_b = (const float*)d_in[4];
  const float* W2     = (const float*)d_in[5];
  const float* b2     = (const float*)d_in[6];
  float* out = (float*)d_out;

  char* ws = (char*)d_ws;
  // ws layout (bytes): apack 81920 | G bf16 4 MiB | Yt bf16 4 MiB  (~8.5 MB)
  short* apack = (short*)(ws);
  short* G     = (short*)(ws + 81920);
  short* Yt    = (short*)(ws + 81920 + 4194304);

  hipLaunchKernelGGL(k1_prep,  dim3(80),  dim3(64),  0, stream, C, W2, apack);
  hipLaunchKernelGGL(k2_gemm,  dim3(512), dim3(256), 0, stream, idx, emb, apack, G, Yt);
  hipLaunchKernelGGL(k3_fused, dim3(64),  dim3(512), 0, stream, G, conv_w, conv_b, Yt, b2, out);
}

// Round 3
// 157.319 us; speedup vs baseline: 1.0491x; 1.0491x over previous
//
#include <hip/hip_runtime.h>

// Problem constants (fixed by the reference)
#define B_   64
#define S_   512
#define P_   300
#define K_   50
#define MPAD 64      // label dim padded to 64 for MFMA M
#define LDX  344     // x_tile row stride in bf16 elems (16B-aligned rows, bank-balanced)
#define LDG  528     // k3 LDS row stride in floats: 8 halo + 512 + 8 halo

typedef short short8v __attribute__((ext_vector_type(8)));
typedef float float4v __attribute__((ext_vector_type(4)));

__device__ __forceinline__ short f2bf(float f) {
  unsigned u = __builtin_bit_cast(unsigned, f);
  u = (u + 0x7FFFu + ((u >> 16) & 1u)) >> 16;  // RNE
  return (short)u;
}
__device__ __forceinline__ float bf2f(short h) {
  return __builtin_bit_cast(float, ((unsigned)(unsigned short)h) << 16);
}

// ---------------------------------------------------------------------------
// K1: normalize C -> l_hat, pad {l_hat, W2} to 64x320 bf16 (zeros), and pack
// into MFMA A-fragment order so K2's A loads are coalesced 16B/lane.
// apack layout: [(mat*4 + mtile)*10 + kstep][lane][8 bf16]
// grid 80 blocks (mat 2 x mtile 4 x kstep 10) x 64 threads.
// ---------------------------------------------------------------------------
__global__ __launch_bounds__(64) void k1_prep(const float* __restrict__ C,
                                              const float* __restrict__ W2,
                                              short* __restrict__ apack) {
  int bid = blockIdx.x;
  int mat = bid / 40;
  int rem = bid - mat * 40;
  int mt  = rem / 10;
  int ks  = rem - mt * 10;
  int lane = threadIdx.x;
  __shared__ float invn[16];
  if (mat == 0) {
    int rl = lane >> 2, q = lane & 3;
    int m = mt * 16 + rl;
    float ss = 0.f;
    if (m < K_) {
      for (int p = q; p < P_; p += 4) { float v = C[m * P_ + p]; ss += v * v; }
    }
    ss += __shfl_xor(ss, 1);
    ss += __shfl_xor(ss, 2);
    if (q == 0) invn[rl] = 1.f / (sqrtf(ss) + 0.001f);
  }
  __syncthreads();
  int ml = lane & 15, quad = lane >> 4;
  int m = mt * 16 + ml;
  const float* src = (mat == 0) ? C : W2;
  short8v v8;
  #pragma unroll
  for (int j = 0; j < 8; ++j) {
    int k = ks * 32 + quad * 8 + j;
    float v = 0.f;
    if (m < K_ && k < P_) {
      v = src[m * P_ + k];
      if (mat == 0) v *= invn[ml];
    }
    v8[j] = f2bf(v);
  }
  *(short8v*)(apack + (size_t)(((mat * 4 + mt) * 10 + ks) * 512 + lane * 8)) = v8;
}

// ---------------------------------------------------------------------------
// K2: per (b, 64-s chunk): gather emb rows -> LDS bf16 (f32 norms en route),
// dual GEMM via 16x16x32 bf16 MFMA:
//   G[b,m,s]  = bf16( (l_hat . x) * 1/(||x||+1e-3) )
//   Yt[b,m,s] = bf16( W2 . x )
// grid 512 x 256. Wave w owns M-rows [16w,16w+16). Only m<50 stored.
// ---------------------------------------------------------------------------
__global__ __launch_bounds__(256) void k2_gemm(const int* __restrict__ idx,
                                               const float* __restrict__ emb,
                                               const short* __restrict__ apack,
                                               short* __restrict__ G,
                                               short* __restrict__ Yt) {
  __shared__ __align__(16) short xt[64][LDX];
  __shared__ float scale_s[64];
  int bid = blockIdx.x;
  int b = bid >> 3, s0 = (bid & 7) * 64;
  int tid = threadIdx.x;
  int w = tid >> 6, lane = tid & 63;

  // stage: wave w loads rows [16w, 16w+16)
  float ssr[16];
  #pragma unroll
  for (int r = 0; r < 16; ++r) {
    int ls = w * 16 + r;
    int row = idx[b * S_ + s0 + ls];
    const float4* src = (const float4*)(emb + (size_t)row * P_);
    float4 v = src[lane];                       // p = 4*lane .. 4*lane+3 (p<256)
    float ss = v.x * v.x + v.y * v.y + v.z * v.z + v.w * v.w;
    short4 h; h.x = f2bf(v.x); h.y = f2bf(v.y); h.z = f2bf(v.z); h.w = f2bf(v.w);
    *(short4*)&xt[ls][4 * lane] = h;
    if (lane < 11) {                            // p = 256..299
      float4 v2 = src[64 + lane];
      ss += v2.x * v2.x + v2.y * v2.y + v2.z * v2.z + v2.w * v2.w;
      short4 h2; h2.x = f2bf(v2.x); h2.y = f2bf(v2.y); h2.z = f2bf(v2.z); h2.w = f2bf(v2.w);
      *(short4*)&xt[ls][256 + 4 * lane] = h2;
    } else if (lane < 16) {                     // zero K-pad cols 300..319
      short4 z = {0, 0, 0, 0};
      *(short4*)&xt[ls][300 + 4 * (lane - 11)] = z;
    }
    ssr[r] = ss;
  }
  #pragma unroll
  for (int r = 0; r < 16; ++r) {
    float ss = ssr[r];
    #pragma unroll
    for (int off = 32; off > 0; off >>= 1) ss += __shfl_xor(ss, off);
    if (lane == 0) scale_s[w * 16 + r] = 1.f / (sqrtf(ss) + 0.001f);
  }
  __syncthreads();

  float4v accG[4] = {}, accY[4] = {};
  int ml = lane & 15, quad = lane >> 4;
  const short8v* a1p = (const short8v*)(apack) + (size_t)((0 * 4 + w) * 10) * 64 + lane;
  const short8v* a2p = (const short8v*)(apack) + (size_t)((1 * 4 + w) * 10) * 64 + lane;
  #pragma unroll
  for (int ks = 0; ks < 10; ++ks) {
    short8v a1 = a1p[ks * 64];
    short8v a2 = a2p[ks * 64];
    int kk = ks * 32 + quad * 8;
    #pragma unroll
    for (int nt = 0; nt < 4; ++nt) {
      short8v bf = *(const short8v*)&xt[nt * 16 + ml][kk];
      accG[nt] = __builtin_amdgcn_mfma_f32_16x16x32_bf16(a1, bf, accG[nt], 0, 0, 0);
      accY[nt] = __builtin_amdgcn_mfma_f32_16x16x32_bf16(a2, bf, accY[nt], 0, 0, 0);
    }
  }

  // epilogue: C/D layout col = lane&15, row = quad*4+reg; store bf16, m<50 only
  #pragma unroll
  for (int nt = 0; nt < 4; ++nt) {
    int sl = nt * 16 + ml;
    float sc = scale_s[sl];
    int sg = s0 + sl;
    #pragma unroll
    for (int reg = 0; reg < 4; ++reg) {
      int m = w * 16 + quad * 4 + reg;
      if (m < K_) {
        G [(size_t)(b * MPAD + m) * S_ + sg] = f2bf(accG[nt][reg] * sc);
        Yt[(size_t)(b * MPAD + m) * S_ + sg] = f2bf(accY[nt][reg]);
      }
    }
  }
}

// ---------------------------------------------------------------------------
// K3 (fused): one block per b (512 threads).
//   stage G[b] as f32 (halo-padded) in LDS  (convert bf16->f32 once at stage)
//   m[s]  = max_{k<50} relu(conv11(G[b,k,s-5..s+5]) + conv_b)   (thread = s)
//   beta  = softmax(m)/S                                        (block reduce)
//   out[b,k] = sum_s beta[s]*Yt[b,k,s] + b2[k]                  (wave per k)
// LDS: 50*528*4 = 105.6 KB + beta 2 KB -> 1 block/CU (64 blocks total, fine).
// ---------------------------------------------------------------------------
__global__ __launch_bounds__(512) void k3_fused(const short* __restrict__ G,
                                                const float* __restrict__ conv_w,
                                                const float* __restrict__ conv_b,
                                                const short* __restrict__ Yt,
                                                const float* __restrict__ b2,
                                                float* __restrict__ out) {
  __shared__ __align__(16) float gt[K_][LDG];
  __shared__ float beta[S_];
  __shared__ float red[8];
  int b = blockIdx.x;
  int tid = threadIdx.x;
  int lane = tid & 63, wv = tid >> 6;

  // zero halos: gt[k][0..8) and gt[k][520..528)
  for (int e = tid; e < K_ * 8; e += 512) {
    int k = e >> 3, j = e & 7;
    gt[k][j] = 0.f;
    gt[k][520 + j] = 0.f;
  }
  // stage rows: wave wv loads rows wv, wv+8, ...; lane covers 8 bf16 (16B),
  // converts to f32, writes 2x float4 (32B) to LDS.
  for (int k = wv; k < K_; k += 8) {
    short8v v = *(const short8v*)(G + (((size_t)(b * MPAD + k)) << 9) + lane * 8);
    float* dst = &gt[k][8 + lane * 8];
    float4 f0, f1;
    f0.x = bf2f(v[0]); f0.y = bf2f(v[1]); f0.z = bf2f(v[2]); f0.w = bf2f(v[3]);
    f1.x = bf2f(v[4]); f1.y = bf2f(v[5]); f1.z = bf2f(v[6]); f1.w = bf2f(v[7]);
    *(float4*)dst = f0;
    *(float4*)(dst + 4) = f1;
  }
  float wvv[11];
  #pragma unroll
  for (int t = 0; t < 11; ++t) wvv[t] = conv_w[t];
  float cb = conv_b[0];
  __syncthreads();

  // conv + relu + max over k; thread owns s = tid
  float mx = 0.f;  // relu >= 0 so 0 is a safe identity
  for (int k = 0; k < K_; ++k) {
    float acc = cb;
    #pragma unroll
    for (int t = 0; t < 11; ++t) acc += wvv[t] * gt[k][3 + tid + t];
    mx = fmaxf(mx, fmaxf(acc, 0.f));
  }

  // block softmax over s (512 threads)
  float r = mx;
  #pragma unroll
  for (int off = 32; off > 0; off >>= 1) r = fmaxf(r, __shfl_xor(r, off));
  if (lane == 0) red[wv] = r;
  __syncthreads();
  float bm = red[0];
  #pragma unroll
  for (int i = 1; i < 8; ++i) bm = fmaxf(bm, red[i]);
  float e = __expf(mx - bm);
  r = e;
  #pragma unroll
  for (int off = 32; off > 0; off >>= 1) r += __shfl_xor(r, off);
  __syncthreads();               // everyone done reading red (max) before rewrite
  if (lane == 0) red[wv] = r;
  __syncthreads();
  float sum = 0.f;
  #pragma unroll
  for (int i = 0; i < 8; ++i) sum += red[i];
  beta[tid] = e / (sum * (float)S_);   // fold 1/S of jnp.mean into beta
  __syncthreads();

  // out[b,k] = sum_s beta[s] * Yt[b,k,s] + b2[k]; wave wv handles k = wv, wv+8, ...
  for (int k = wv; k < K_; k += 8) {
    short8v y = *(const short8v*)(Yt + (((size_t)(b * MPAD + k)) << 9) + lane * 8);
    const float4* bp = (const float4*)&beta[lane * 8];
    float4 b0 = bp[0], b1 = bp[1];
    float acc = b0.x * bf2f(y[0]) + b0.y * bf2f(y[1]) +
                b0.z * bf2f(y[2]) + b0.w * bf2f(y[3]) +
                b1.x * bf2f(y[4]) + b1.y * bf2f(y[5]) +
                b1.z * bf2f(y[6]) + b1.w * bf2f(y[7]);
    #pragma unroll
    for (int off = 32; off > 0; off >>= 1) acc += __shfl_xor(acc, off);
    if (lane == 0) out[b * K_ + k] = acc + b2[k];
  }
}

// ---------------------------------------------------------------------------
extern "C" void kernel_launch(void* const* d_in, const int* in_sizes, int n_in,
                              void* d_out, int out_size, void* d_ws, size_t ws_size,
                              hipStream_t stream) {
  const int*   idx    = (const int*)  d_in[0];
  const float* emb    = (const float*)d_in[1];
  const float* C      = (const float*)d_in[2];
  const float* conv_w = (const float*)d_in[3];
  const float* conv_b = (const float*)d_in[4];
  const float* W2     = (const float*)d_in[5];
  const float* b2     = (const float*)d_in[6];
  float* out = (float*)d_out;

  char* ws = (char*)d_ws;
  // ws layout (bytes): apack 81920 | G bf16 4 MiB | Yt bf16 4 MiB  (~8.5 MB)
  short* apack = (short*)(ws);
  short* G     = (short*)(ws + 81920);
  short* Yt    = (short*)(ws + 81920 + 4194304);

  hipLaunchKernelGGL(k1_prep,  dim3(80),  dim3(64),  0, stream, C, W2, apack);
  hipLaunchKernelGGL(k2_gemm,  dim3(512), dim3(256), 0, stream, idx, emb, apack, G, Yt);
  hipLaunchKernelGGL(k3_fused, dim3(64),  dim3(512), 0, stream, G, conv_w, conv_b, Yt, b2, out);
}